// Round 8
// baseline (1115.215 us; speedup 1.0000x reference)
//
#include <hip/hip_runtime.h>
#include <math.h>

// Problem constants
#define Bsz 16
#define Nn  1024
#define Ee  128
#define CTX 384
#define DIN 768
#define DST 16
#define DTR 24
#define ROWS (Bsz*Nn)   // 16384

typedef __attribute__((ext_vector_type(8))) short short8;
typedef __attribute__((ext_vector_type(4))) float f32x4;

__device__ inline float fexp2(float x)
{
#if __has_builtin(__builtin_amdgcn_exp2f)
    return __builtin_amdgcn_exp2f(x);
#else
    return __expf(x * 0.6931471805599453f);
#endif
}

// ---------------------------------------------------------------------------
// split3: fp32 -> 3 bf16 planes (h trunc, m trunc, l rne). Product terms
// hh+hm+mh+hl+mm+lh give ~2^-23 rel error.
// ---------------------------------------------------------------------------
__device__ inline void split3(float v, ushort& h, ushort& m, ushort& l)
{
    unsigned u = __float_as_uint(v);
    h = (ushort)(u >> 16);
    float vh = __uint_as_float((unsigned)h << 16);
    float r = v - vh;
    unsigned ur = __float_as_uint(r);
    m = (ushort)(ur >> 16);
    float vm = __uint_as_float((unsigned)m << 16);
    float r2 = r - vm;
    unsigned u2 = __float_as_uint(r2);
    u2 += 0x7fffu + ((u2 >> 16) & 1u);
    l = (ushort)(u2 >> 16);
}

// ---------------------------------------------------------------------------
// RMS row scales over the virtual ctx = [graph_emb(256) | node_emb(128)]
// ---------------------------------------------------------------------------
__global__ __launch_bounds__(128) void rms_k(
    const float* __restrict__ ge, const float* __restrict__ ne,
    float* __restrict__ rs)
{
    int row = blockIdx.x;            // b*1024 + n
    int b = row >> 10;
    int tid = threadIdx.x;
    float ssq = 0.f;
    #pragma unroll
    for (int k = 0; k < 3; ++k) {
        int idx = tid + k * 128;
        float v = (idx < 256) ? ge[b * 256 + idx]
                              : ne[(long long)row * 128 + (idx - 256)];
        ssq += v * v;
    }
    __shared__ float sh[128];
    sh[tid] = ssq;
    __syncthreads();
    for (int w = 64; w > 0; w >>= 1) {
        if (tid < w) sh[tid] += sh[tid + w];
        __syncthreads();
    }
    if (tid == 0) rs[row] = rsqrtf(sh[0] * (1.f / 384.f) + 1e-6f);
}

__global__ __launch_bounds__(256) void zero_k(float* __restrict__ p, int n)
{
    int i = blockIdx.x * 256 + threadIdx.x;
    if (i < n) p[i] = 0.f;
}

// ---------------------------------------------------------------------------
// presplit_ctx_k: ctxP[row][kb][3][32] = split3(rmsnorm(ctx)).
// ---------------------------------------------------------------------------
__global__ __launch_bounds__(256) void presplit_ctx_k(
    const float* __restrict__ ge, const float* __restrict__ ne,
    const float* __restrict__ rs, const float* __restrict__ cw,
    ushort* __restrict__ ctxP)
{
    int idx = blockIdx.x * 256 + threadIdx.x;   // 0 .. 196607
    int row = idx / 12;
    int kb = idx - row * 12;
    float rsv = rs[row];
    int b = row >> 10;
    int c0 = kb * 32;
    ushort hb[32], mb[32], lb[32];
    #pragma unroll
    for (int e = 0; e < 32; ++e) {
        int col = c0 + e;
        float v = (col < 256) ? ge[b * 256 + col]
                              : ne[(long long)row * 128 + (col - 256)];
        v *= rsv * cw[col];
        split3(v, hb[e], mb[e], lb[e]);
    }
    ushort* dst = ctxP + (long long)row * 1152 + kb * 96;
    #pragma unroll
    for (int w8 = 0; w8 < 4; ++w8) {
        short8 v;
        #pragma unroll
        for (int e = 0; e < 8; ++e) v[e] = (short)hb[w8 * 8 + e];
        *(short8*)(dst + w8 * 8) = v;
    }
    #pragma unroll
    for (int w8 = 0; w8 < 4; ++w8) {
        short8 v;
        #pragma unroll
        for (int e = 0; e < 8; ++e) v[e] = (short)mb[w8 * 8 + e];
        *(short8*)(dst + 32 + w8 * 8) = v;
    }
    #pragma unroll
    for (int w8 = 0; w8 < 4; ++w8) {
        short8 v;
        #pragma unroll
        for (int e = 0; e < 8; ++e) v[e] = (short)lb[w8 * 8 + e];
        *(short8*)(dst + 64 + w8 * 8) = v;
    }
}

// ---------------------------------------------------------------------------
// presplit_w_k: W[K][N] fp32 -> WP[n][kb][3][32] (transposed plane format).
// ---------------------------------------------------------------------------
__global__ __launch_bounds__(256) void presplit_w_k(
    const float* __restrict__ W, int N, ushort* __restrict__ WP, int K3)
{
    int l = threadIdx.x & 63;
    int kq = threadIdx.x >> 6;
    int n = blockIdx.x * 64 + l;
    int kb = blockIdx.y * 4 + kq;
    ushort hb[32], mb[32], lb[32];
    #pragma unroll
    for (int i = 0; i < 32; ++i) {
        float v = W[(long long)(kb * 32 + i) * N + n];
        split3(v, hb[i], mb[i], lb[i]);
    }
    ushort* dst = WP + (long long)n * K3 + kb * 96;
    #pragma unroll
    for (int w8 = 0; w8 < 4; ++w8) {
        short8 v;
        #pragma unroll
        for (int e = 0; e < 8; ++e) v[e] = (short)hb[w8 * 8 + e];
        *(short8*)(dst + w8 * 8) = v;
    }
    #pragma unroll
    for (int w8 = 0; w8 < 4; ++w8) {
        short8 v;
        #pragma unroll
        for (int e = 0; e < 8; ++e) v[e] = (short)mb[w8 * 8 + e];
        *(short8*)(dst + 32 + w8 * 8) = v;
    }
    #pragma unroll
    for (int w8 = 0; w8 < 4; ++w8) {
        short8 v;
        #pragma unroll
        for (int e = 0; e < 8; ++e) v[e] = (short)lb[w8 * 8 + e];
        *(short8*)(dst + 64 + w8 * 8) = v;
    }
}

// ---------------------------------------------------------------------------
// mgemm_p_k: C = A @ B^T-planes, 128x128 tile, 4 waves, bf16x6 via 3 planes.
// ---------------------------------------------------------------------------
template<int ASRC, int BSRC, int EPI>
__global__ __launch_bounds__(256, 2) void mgemm_p_k(
    const ushort* __restrict__ PA, const float* __restrict__ Af,
    int ldaF, int sAp, long long aB,
    const ushort* __restrict__ PB, const float* __restrict__ Bf,
    int ldbF, int sBp, long long bB,
    float* __restrict__ Cf, ushort* __restrict__ CP,
    int ldc, int sCp, long long cB,
    int K,
    const float* __restrict__ ge, const float* __restrict__ ne,
    const float* __restrict__ gsink)
{
    __shared__ __align__(16) ushort As[128][128];
    __shared__ __align__(16) ushort Bs[128][128];
    int t = threadIdx.x;
    int n0 = blockIdx.x * 128, m0 = blockIdx.y * 128, bz = blockIdx.z;
    const ushort* pa = PA + (long long)bz * aB + (long long)m0 * sAp;
    const float*  fa = Af + (long long)bz * aB + (long long)m0 * ldaF;
    const ushort* pb = PB + (long long)bz * bB + (long long)n0 * sBp;
    const float*  fb = Bf + (long long)bz * bB + (long long)n0 * ldbF;

    int wave = t >> 6, lane = t & 63;
    int wm = (wave & 1) * 64, wn = (wave >> 1) * 64;
    int lm = lane & 15, lq = lane >> 4;
    f32x4 acc[4][4] = {};

    int nkb = K >> 5;
    for (int kb = 0; kb < nkb; ++kb) {
        int r = t >> 1;
        int sw = r & 15;
        // ---- stage A ----
        if (ASRC == 0) {
            int g0 = (t & 1) * 6;
            const ushort* src = pa + (long long)r * sAp + kb * 96 + g0 * 8;
            #pragma unroll
            for (int jj = 0; jj < 6; ++jj) {
                short8 v = *(const short8*)(src + jj * 8);
                *(short8*)&As[r][((g0 + jj) ^ sw) * 8] = v;
            }
        } else {
            int c0 = (t & 1) * 16;
            const float* src = fa + (long long)r * ldaF + kb * 32 + c0;
            ushort hb[16], mb[16], lb[16];
            #pragma unroll
            for (int e = 0; e < 16; ++e) split3(src[e], hb[e], mb[e], lb[e]);
            int gq = (t & 1) * 2;
            #pragma unroll
            for (int half = 0; half < 2; ++half) {
                short8 vh, vm, vl;
                #pragma unroll
                for (int e = 0; e < 8; ++e) {
                    vh[e] = (short)hb[half * 8 + e];
                    vm[e] = (short)mb[half * 8 + e];
                    vl[e] = (short)lb[half * 8 + e];
                }
                *(short8*)&As[r][((0 + gq + half) ^ sw) * 8] = vh;
                *(short8*)&As[r][((4 + gq + half) ^ sw) * 8] = vm;
                *(short8*)&As[r][((8 + gq + half) ^ sw) * 8] = vl;
            }
        }
        // ---- stage B ----
        if (BSRC == 0) {
            int g0 = (t & 1) * 6;
            const ushort* src = pb + (long long)r * sBp + kb * 96 + g0 * 8;
            #pragma unroll
            for (int jj = 0; jj < 6; ++jj) {
                short8 v = *(const short8*)(src + jj * 8);
                *(short8*)&Bs[r][((g0 + jj) ^ sw) * 8] = v;
            }
        } else {
            int c0 = (t & 1) * 16;
            const float* src = fb + (long long)r * ldbF + kb * 32 + c0;
            ushort hb[16], mb[16], lb[16];
            #pragma unroll
            for (int e = 0; e < 16; ++e) split3(src[e], hb[e], mb[e], lb[e]);
            int gq = (t & 1) * 2;
            #pragma unroll
            for (int half = 0; half < 2; ++half) {
                short8 vh, vm, vl;
                #pragma unroll
                for (int e = 0; e < 8; ++e) {
                    vh[e] = (short)hb[half * 8 + e];
                    vm[e] = (short)mb[half * 8 + e];
                    vl[e] = (short)lb[half * 8 + e];
                }
                *(short8*)&Bs[r][((0 + gq + half) ^ sw) * 8] = vh;
                *(short8*)&Bs[r][((4 + gq + half) ^ sw) * 8] = vm;
                *(short8*)&Bs[r][((8 + gq + half) ^ sw) * 8] = vl;
            }
        }
        __syncthreads();
        // ---- fragments + 6-term MFMA ----
        short8 ah[4], am[4], al[4];
        #pragma unroll
        for (int i = 0; i < 4; ++i) {
            int R = wm + i * 16 + lm;
            int rw = R & 15;
            ah[i] = *(const short8*)&As[R][((0 + lq) ^ rw) * 8];
            am[i] = *(const short8*)&As[R][((4 + lq) ^ rw) * 8];
            al[i] = *(const short8*)&As[R][((8 + lq) ^ rw) * 8];
        }
        #pragma unroll
        for (int j = 0; j < 4; ++j) {
            int Rn = wn + j * 16 + lm;
            int rw = Rn & 15;
            short8 bh = *(const short8*)&Bs[Rn][((0 + lq) ^ rw) * 8];
            short8 bm = *(const short8*)&Bs[Rn][((4 + lq) ^ rw) * 8];
            short8 bl = *(const short8*)&Bs[Rn][((8 + lq) ^ rw) * 8];
            #pragma unroll
            for (int i = 0; i < 4; ++i)
                acc[i][j] = __builtin_amdgcn_mfma_f32_16x16x32_bf16(ah[i], bh, acc[i][j], 0, 0, 0);
            #pragma unroll
            for (int i = 0; i < 4; ++i)
                acc[i][j] = __builtin_amdgcn_mfma_f32_16x16x32_bf16(ah[i], bm, acc[i][j], 0, 0, 0);
            #pragma unroll
            for (int i = 0; i < 4; ++i)
                acc[i][j] = __builtin_amdgcn_mfma_f32_16x16x32_bf16(am[i], bh, acc[i][j], 0, 0, 0);
            #pragma unroll
            for (int i = 0; i < 4; ++i)
                acc[i][j] = __builtin_amdgcn_mfma_f32_16x16x32_bf16(ah[i], bl, acc[i][j], 0, 0, 0);
            #pragma unroll
            for (int i = 0; i < 4; ++i)
                acc[i][j] = __builtin_amdgcn_mfma_f32_16x16x32_bf16(am[i], bm, acc[i][j], 0, 0, 0);
            #pragma unroll
            for (int i = 0; i < 4; ++i)
                acc[i][j] = __builtin_amdgcn_mfma_f32_16x16x32_bf16(al[i], bh, acc[i][j], 0, 0, 0);
        }
        __syncthreads();
    }

    // ---- epilogue: D col=lane&15, row=lq*4+reg ----
    #pragma unroll
    for (int i = 0; i < 4; ++i) {
        #pragma unroll
        for (int rg = 0; rg < 4; ++rg) {
            int m = m0 + wm + i * 16 + lq * 4 + rg;
            #pragma unroll
            for (int j = 0; j < 4; ++j) {
                int n = n0 + wn + j * 16 + lm;
                float x = acc[i][j][rg];
                if (EPI == 0) {
                    Cf[(long long)m * ldc + n] = x;
                } else if (EPI == 1) {
                    ushort h, mm_, l;
                    split3(x, h, mm_, l);
                    ushort* dst = CP + (long long)m * sCp + (n >> 5) * 96 + (n & 31);
                    dst[0] = h; dst[32] = mm_; dst[64] = l;
                } else if (EPI == 2) {
                    x += (n < 256) ? ge[(m >> 10) * 256 + n]
                                   : ne[(long long)m * 128 + (n - 256)];
                    Cf[(long long)m * ldc + n] = x;
                } else {
                    long long off = (long long)bz * cB + (long long)m * ldc + n;
                    Cf[off] = x + gsink[off];
                }
            }
        }
    }
}

// ---------------------------------------------------------------------------
// dbc_k: dbc[16384][56] = uC[16384][768] @ W_x[768][56]. Skinny-N fp32 GEMM.
// ---------------------------------------------------------------------------
__global__ __launch_bounds__(256) void dbc_k(
    const float* __restrict__ uC, const float* __restrict__ Wx,
    float* __restrict__ dbc)
{
    __shared__ float As[32][68];   // [k][row], 64 rows padded to 68
    __shared__ float Bs[32][64];   // [k][col], 56 cols padded to 64
    int t = threadIdx.x;
    int r0 = blockIdx.x * 64;
    int tr = t >> 4, tc = t & 15;
    float acc[4][4] = {};

    for (int k0 = 0; k0 < 768; k0 += 32) {
        #pragma unroll
        for (int i = 0; i < 2; ++i) {
            int idx = t + i * 256;           // 0..511
            int r = idx >> 3;                // 0..63
            int kq = (idx & 7) * 4;          // 0..28
            float4 v = *(const float4*)(uC + (long long)(r0 + r) * 768 + k0 + kq);
            As[kq + 0][r] = v.x;
            As[kq + 1][r] = v.y;
            As[kq + 2][r] = v.z;
            As[kq + 3][r] = v.w;
        }
        #pragma unroll
        for (int i = 0; i < 2; ++i) {
            int idx = t + i * 256;           // need 32*14 = 448
            if (idx < 448) {
                int kk = idx / 14;
                int c4 = (idx - kk * 14) * 4;
                float4 v = *(const float4*)(Wx + (long long)(k0 + kk) * 56 + c4);
                *(float4*)&Bs[kk][c4] = v;
            }
        }
        __syncthreads();
        #pragma unroll
        for (int kk = 0; kk < 32; ++kk) {
            float4 a = *(const float4*)&As[kk][tr * 4];
            float4 b = *(const float4*)&Bs[kk][tc * 4];
            float av[4] = {a.x, a.y, a.z, a.w};
            float bv[4] = {b.x, b.y, b.z, b.w};
            #pragma unroll
            for (int i = 0; i < 4; ++i)
                #pragma unroll
                for (int j = 0; j < 4; ++j)
                    acc[i][j] = fmaf(av[i], bv[j], acc[i][j]);
        }
        __syncthreads();
    }

    if (tc < 14) {                           // cols tc*4..tc*4+3 < 56
        #pragma unroll
        for (int i = 0; i < 4; ++i) {
            int row = r0 + tr * 4 + i;
            *(float4*)&dbc[(long long)row * 56 + tc * 4] =
                make_float4(acc[i][0], acc[i][1], acc[i][2], acc[i][3]);
        }
    }
}

// ---------------------------------------------------------------------------
// gemm_s_k: fp32 VALU GEMM (kept for delta: K=24). EPI 6 = softplus(+bias[col])
// ---------------------------------------------------------------------------
template<int EPI>
__global__ __launch_bounds__(256) void gemm_s_k(
    const float* __restrict__ A, int lda,
    const float* __restrict__ Bm, int ldb,
    float* __restrict__ C, int ldc,
    int M, int N, int K,
    const float* __restrict__ bias)
{
    __shared__ float As[16][132];
    __shared__ float Bs[16][132];
    int t = threadIdx.x;
    int gn0 = blockIdx.x * 128;
    int rowBase = blockIdx.y * 128;
    float acc[8][8] = {};
    int cx4 = (t & 15) * 4;
    int ry4 = (t >> 4) * 4;

    for (int k0 = 0; k0 < K; k0 += 16) {
        {
            int r = t >> 1;
            int kq = (t & 1) * 8;
            const float* Ap = A + (long long)(rowBase + r) * lda + k0 + kq;
            float av[8];
            #pragma unroll
            for (int j = 0; j < 8; ++j)
                av[j] = (k0 + kq + j < K) ? Ap[j] : 0.f;
            #pragma unroll
            for (int j = 0; j < 8; ++j) As[kq + j][r] = av[j];
        }
        {
            int kk = t >> 4;
            int bn0 = (t & 15) * 8;
            const float* Bp = Bm + (long long)(k0 + kk) * ldb + gn0 + bn0;
            float4 v0 = make_float4(0.f, 0.f, 0.f, 0.f), v1 = v0;
            if (k0 + kk < K) {
                if (gn0 + bn0 + 7 < N) {
                    v0 = *(const float4*)Bp;
                    v1 = *(const float4*)(Bp + 4);
                } else {
                    float tmp[8];
                    #pragma unroll
                    for (int j = 0; j < 8; ++j)
                        tmp[j] = (gn0 + bn0 + j < N) ? Bp[j] : 0.f;
                    v0 = make_float4(tmp[0], tmp[1], tmp[2], tmp[3]);
                    v1 = make_float4(tmp[4], tmp[5], tmp[6], tmp[7]);
                }
            }
            *(float4*)&Bs[kk][bn0] = v0;
            *(float4*)&Bs[kk][bn0 + 4] = v1;
        }
        __syncthreads();
        #pragma unroll
        for (int kk = 0; kk < 16; ++kk) {
            float4 a0 = *(const float4*)&As[kk][ry4];
            float4 a1 = *(const float4*)&As[kk][ry4 + 64];
            float4 b0 = *(const float4*)&Bs[kk][cx4];
            float4 b1 = *(const float4*)&Bs[kk][cx4 + 64];
            float av[8] = {a0.x, a0.y, a0.z, a0.w, a1.x, a1.y, a1.z, a1.w};
            float bv[8] = {b0.x, b0.y, b0.z, b0.w, b1.x, b1.y, b1.z, b1.w};
            #pragma unroll
            for (int i = 0; i < 8; ++i)
                #pragma unroll
                for (int j = 0; j < 8; ++j)
                    acc[i][j] = fmaf(av[i], bv[j], acc[i][j]);
        }
        __syncthreads();
    }

    #pragma unroll
    for (int i = 0; i < 8; ++i) {
        int gm = rowBase + (i >> 2) * 64 + ry4 + (i & 3);
        #pragma unroll
        for (int jh = 0; jh < 2; ++jh) {
            int gn = gn0 + jh * 64 + cx4;
            float v[4];
            #pragma unroll
            for (int e = 0; e < 4; ++e) {
                float x = acc[i][jh * 4 + e];
                if (EPI == 6) {
                    float s = x + bias[gn + e];
                    x = fmaxf(s, 0.f) + log1pf(expf(-fabsf(s)));
                }
                v[e] = x;
            }
            if (gn + 3 < N) {
                *(float4*)&C[(long long)gm * ldc + gn] =
                    make_float4(v[0], v[1], v[2], v[3]);
            } else {
                #pragma unroll
                for (int e = 0; e < 4; ++e)
                    if (gn + e < N) C[(long long)gm * ldc + gn + e] = v[e];
            }
        }
    }
}

// ---------------------------------------------------------------------------
// Depthwise causal conv (K=4) + bias + SiLU, ROW-MAJOR out: uC[b*1024+n][d]
// ---------------------------------------------------------------------------
__global__ __launch_bounds__(256) void conv_r_k(
    const float* __restrict__ uB, const float* __restrict__ cw,
    const float* __restrict__ cb, float* __restrict__ uC)
{
    __shared__ float tile[67][33];
    int b = blockIdx.z, d0 = blockIdx.y * 32, n0 = blockIdx.x * 64;
    int tid = threadIdx.x;
    for (int i = tid; i < 67 * 32; i += 256) {
        int r = i >> 5, c = i & 31;
        int n = n0 - 3 + r;
        tile[r][c] = (n >= 0) ? uB[((long long)(b * 1024 + n)) * 768 + d0 + c] : 0.f;
    }
    __syncthreads();
    int dc = tid & 31;
    int nr = tid >> 5;
    int d = d0 + dc;
    float w0 = cw[d * 4 + 0], w1 = cw[d * 4 + 1];
    float w2 = cw[d * 4 + 2], w3 = cw[d * 4 + 3];
    float bb = cb[d];
    #pragma unroll
    for (int it = 0; it < 8; ++it) {
        int nl = nr + it * 8;
        float acc = bb;
        acc = fmaf(tile[nl][dc],     w0, acc);
        acc = fmaf(tile[nl + 1][dc], w1, acc);
        acc = fmaf(tile[nl + 2][dc], w2, acc);
        acc = fmaf(tile[nl + 3][dc], w3, acc);
        float sv = acc / (1.f + __expf(-acc));
        uC[((long long)(b * 1024 + n0 + nl)) * 768 + d] = sv;
    }
}

// ---------------------------------------------------------------------------
// S6 scan, associative 3-phase, ROW-MAJOR delta/u/z/y.
// ---------------------------------------------------------------------------
#define HIN_CSTR (16LL * 16 * 768)   // floats per chunk slot

__global__ __launch_bounds__(256) void scan_p0_k(
    const float* __restrict__ dB, const float* __restrict__ uC,
    const float* __restrict__ dbc, const float* __restrict__ A_log,
    float* __restrict__ hin, float* __restrict__ Pbuf)
{
    int d = blockIdx.x * 256 + threadIdx.x;
    int c = blockIdx.y;              // 0..14
    int b = blockIdx.z;
    int n0 = c * 64;
    long long rowbase = (long long)b * 1024 + n0;
    const float* dR = dB + rowbase * 768 + d;
    const float* uR = uC + rowbase * 768 + d;

    float a2[16], P[16], Q[16];
    #pragma unroll
    for (int s = 0; s < 16; ++s) {
        a2[s] = -__expf(A_log[d * 16 + s]) * 1.44269504088896340736f;
        P[s] = 1.f;
        Q[s] = 0.f;
    }

    for (int i0 = 0; i0 < 64; i0 += 4) {
        float dv[4], uv[4];
        #pragma unroll
        for (int j = 0; j < 4; ++j) {
            long long i = i0 + j;
            dv[j] = dR[i * 768];
            uv[j] = uR[i * 768];
        }
        #pragma unroll
        for (int j = 0; j < 4; ++j) {
            int row = __builtin_amdgcn_readfirstlane((int)rowbase + i0 + j);
            const float* br = dbc + (long long)row * 56;
            float Bv[16];
            #pragma unroll
            for (int q = 0; q < 4; ++q) {
                float4 bq = *(const float4*)(br + 24 + q * 4);
                Bv[q * 4 + 0] = bq.x; Bv[q * 4 + 1] = bq.y;
                Bv[q * 4 + 2] = bq.z; Bv[q * 4 + 3] = bq.w;
            }
            float x = dv[j] * uv[j];
            #pragma unroll
            for (int s = 0; s < 16; ++s) {
                float dA = fexp2(dv[j] * a2[s]);
                Q[s] = fmaf(dA, Q[s], x * Bv[s]);
                P[s] *= dA;
            }
        }
    }

    float* qd = hin  + (long long)(c + 1) * HIN_CSTR + ((long long)b * 16) * 768 + d;
    float* pd = Pbuf + (long long)c * HIN_CSTR + ((long long)b * 16) * 768 + d;
    #pragma unroll
    for (int s = 0; s < 16; ++s) {
        qd[(long long)s * 768] = Q[s];
        pd[(long long)s * 768] = P[s];
    }
}

__global__ __launch_bounds__(256) void scan_comb_k(
    float* __restrict__ hin, const float* __restrict__ Pbuf)
{
    int d = blockIdx.x * 256 + threadIdx.x;
    int s = blockIdx.y, b = blockIdx.z;
    long long off = ((long long)b * 16 + s) * 768 + d;
    float h = 0.f;
    hin[off] = 0.f;                          // chunk 0 checkpoint
    #pragma unroll
    for (int c = 1; c < 16; ++c) {
        float q = hin[(long long)c * HIN_CSTR + off];
        float p = Pbuf[(long long)(c - 1) * HIN_CSTR + off];
        h = fmaf(p, h, q);
        hin[(long long)c * HIN_CSTR + off] = h;
    }
}

__global__ __launch_bounds__(256) void scan_p2_k(
    const float* __restrict__ dB, float* uyC, const float* __restrict__ zB,
    const float* __restrict__ dbc, const float* __restrict__ hin,
    const float* __restrict__ A_log, const float* __restrict__ Dp)
{
    int d = blockIdx.x * 256 + threadIdx.x;
    int c = blockIdx.y;
    int b = blockIdx.z;
    int n0 = c * 64;
    long long rowbase = (long long)b * 1024 + n0;
    const float* dR = dB  + rowbase * 768 + d;
    const float* uR = uyC + rowbase * 768 + d;
    const float* zR = zB  + rowbase * 768 + d;
    float*       yR = uyC + rowbase * 768 + d;

    float a2[16], h[16];
    #pragma unroll
    for (int s = 0; s < 16; ++s)
        a2[s] = -__expf(A_log[d * 16 + s]) * 1.44269504088896340736f;
    const float* hp = hin + (long long)c * HIN_CSTR + ((long long)b * 16) * 768 + d;
    #pragma unroll
    for (int s = 0; s < 16; ++s)
        h[s] = hp[(long long)s * 768];
    float dp = Dp[d];

    for (int i0 = 0; i0 < 64; i0 += 4) {
        float dv[4], uv[4], zv[4];
        #pragma unroll
        for (int j = 0; j < 4; ++j) {
            long long i = i0 + j;
            dv[j] = dR[i * 768];
            uv[j] = uR[i * 768];
            zv[j] = zR[i * 768];
        }
        float ya[4];
        #pragma unroll
        for (int j = 0; j < 4; ++j) {
            int row = __builtin_amdgcn_readfirstlane((int)rowbase + i0 + j);
            const float* br = dbc + (long long)row * 56;
            float Bv[16], Cv[16];
            #pragma unroll
            for (int q = 0; q < 4; ++q) {
                float4 bq = *(const float4*)(br + 24 + q * 4);
                float4 cq = *(const float4*)(br + 40 + q * 4);
                Bv[q * 4 + 0] = bq.x; Bv[q * 4 + 1] = bq.y;
                Bv[q * 4 + 2] = bq.z; Bv[q * 4 + 3] = bq.w;
                Cv[q * 4 + 0] = cq.x; Cv[q * 4 + 1] = cq.y;
                Cv[q * 4 + 2] = cq.z; Cv[q * 4 + 3] = cq.w;
            }
            float x = dv[j] * uv[j];
            float y = 0.f;
            #pragma unroll
            for (int s = 0; s < 16; ++s) {
                float dA = fexp2(dv[j] * a2[s]);
                h[s] = fmaf(dA, h[s], x * Bv[s]);
                y = fmaf(h[s], Cv[s], y);
            }
            float z = zv[j];
            ya[j] = (y + dp * uv[j]) * (z / (1.f + __expf(-z)));
        }
        #pragma unroll
        for (int j = 0; j < 4; ++j)
            yR[(long long)(i0 + j) * 768] = ya[j];
    }
}

// ---------------------------------------------------------------------------
// Sinkhorn on la = la0 - R_i - C_j (never materialized).
// col_lse_part: initial col pass (R = 0 vector). col_comb_k: chunk combine.
// sink_rowcol_k: FUSED row pass + next col partials, one la0 read.
// final2_k: computes R5 in-kernel, then argmax/log_prob/entropy.
// ---------------------------------------------------------------------------
__global__ __launch_bounds__(256) void col_lse_part(
    const float* __restrict__ la0, const float* __restrict__ R,
    float2* __restrict__ cpart)
{
    int j = blockIdx.x * 256 + threadIdx.x;
    int ch = blockIdx.y;
    int b = blockIdx.z;
    const float* base = la0 + (long long)b * 1024 * 1024 + (long long)ch * 64 * 1024 + j;
    const float* Rb = R + b * 1024 + ch * 64;
    float m = -INFINITY, sum = 0.f;
    for (int i = 0; i < 64; ++i) {
        float x = base[(long long)i * 1024] - Rb[i];
        float nm = fmaxf(m, x);
        sum = sum * expf(m - nm) + expf(x - nm);
        m = nm;
    }
    cpart[(long long)(b * 16 + ch) * 1024 + j] = make_float2(m, sum);
}

__global__ __launch_bounds__(256) void col_comb_k(
    const float2* __restrict__ cpart, float* __restrict__ Cv)
{
    int idx = blockIdx.x * 256 + threadIdx.x;
    int b = idx >> 10, j = idx & 1023;
    float m = -INFINITY, sum = 0.f;
    #pragma unroll
    for (int ch = 0; ch < 16; ++ch) {
        float2 p = cpart[(long long)(b * 16 + ch) * 1024 + j];
        float nm = fmaxf(m, p.x);
        sum = sum * expf(m - nm) + p.y * expf(p.x - nm);
        m = nm;
    }
    Cv[idx] = m + logf(sum);
}

__global__ __launch_bounds__(512) void sink_rowcol_k(
    const float* __restrict__ la0, const float* __restrict__ Cv,
    float2* __restrict__ cpart)
{
    __shared__ float cmS[8][1024];
    __shared__ float csS[8][1024];
    int t = threadIdx.x;
    int wave = t >> 6, lane = t & 63;
    int ch = blockIdx.x, b = blockIdx.y;
    const float* base = la0 + (long long)b * (1024 * 1024)
                      + (long long)(ch * 64 + wave * 8) * 1024;
    const float* Cb = Cv + b * 1024;

    float cv[16];
    #pragma unroll
    for (int q = 0; q < 4; ++q) {
        float4 c4 = *(const float4*)(Cb + q * 256 + lane * 4);
        cv[q * 4 + 0] = c4.x; cv[q * 4 + 1] = c4.y;
        cv[q * 4 + 2] = c4.z; cv[q * 4 + 3] = c4.w;
    }
    float cm[16], cs[16];
    #pragma unroll
    for (int k = 0; k < 16; ++k) { cm[k] = -INFINITY; cs[k] = 0.f; }

    for (int rr = 0; rr < 8; ++rr) {
        const float* row = base + (long long)rr * 1024;
        float v[16];
        #pragma unroll
        for (int q = 0; q < 4; ++q) {
            float4 r4 = *(const float4*)(row + q * 256 + lane * 4);
            v[q * 4 + 0] = r4.x; v[q * 4 + 1] = r4.y;
            v[q * 4 + 2] = r4.z; v[q * 4 + 3] = r4.w;
        }
        // row LSE over (v - cv), wave-wide
        float m = -INFINITY;
        #pragma unroll
        for (int k = 0; k < 16; ++k) m = fmaxf(m, v[k] - cv[k]);
        float s = 0.f;
        #pragma unroll
        for (int k = 0; k < 16; ++k) s += expf(v[k] - cv[k] - m);
        #pragma unroll
        for (int off = 1; off < 64; off <<= 1) {
            float m2 = __shfl_xor(m, off);
            float s2 = __shfl_xor(s, off);
            float nm = fmaxf(m, m2);
            s = s * expf(m - nm) + s2 * expf(m2 - nm);
            m = nm;
        }
        float R = m + logf(s);
        // col partial update with val = v - R
        #pragma unroll
        for (int k = 0; k < 16; ++k) {
            float val = v[k] - R;
            float nm = fmaxf(cm[k], val);
            cs[k] = cs[k] * expf(cm[k] - nm) + expf(val - nm);
            cm[k] = nm;
        }
    }
    // stash wave-local col partials
    #pragma unroll
    for (int q = 0; q < 4; ++q) {
        *(float4*)&cmS[wave][q * 256 + lane * 4] =
            make_float4(cm[q * 4 + 0], cm[q * 4 + 1], cm[q * 4 + 2], cm[q * 4 + 3]);
        *(float4*)&csS[wave][q * 256 + lane * 4] =
            make_float4(cs[q * 4 + 0], cs[q * 4 + 1], cs[q * 4 + 2], cs[q * 4 + 3]);
    }
    __syncthreads();
    // combine 8 waves per column; 512 threads x 2 cols
    #pragma unroll
    for (int jj = 0; jj < 2; ++jj) {
        int j = t * 2 + jj;
        float m = -INFINITY, s = 0.f;
        #pragma unroll
        for (int w = 0; w < 8; ++w) {
            float m2 = cmS[w][j], s2 = csS[w][j];
            float nm = fmaxf(m, m2);
            s = s * expf(m - nm) + s2 * expf(m2 - nm);
            m = nm;
        }
        cpart[(long long)(b * 16 + ch) * 1024 + j] = make_float2(m, s);
    }
}

__global__ __launch_bounds__(256) void final2_k(
    const float* __restrict__ la0, const float* __restrict__ Cv,
    const float* __restrict__ gs, float* __restrict__ out)
{
    int r = blockIdx.x;
    int b = r >> 10;
    const float* row = la0 + (long long)r * 1024;
    const float* gr = gs + (long long)r * 1024;
    const float* Cb = Cv + b * 1024;
    int tid = threadIdx.x;
    __shared__ float xs[1024];
    __shared__ float sm[256], ss[256];

    // phase 1: x = row - C5, stash in LDS, row LSE -> R5
    float m = -INFINITY, s = 0.f;
    #pragma unroll
    for (int k = 0; k < 4; ++k) {
        int j = tid + k * 256;
        float x = row[j] - Cb[j];
        xs[j] = x;
        float nm = fmaxf(m, x);
        s = s * expf(m - nm) + expf(x - nm);
        m = nm;
    }
    sm[tid] = m; ss[tid] = s;
    __syncthreads();
    for (int w = 128; w > 0; w >>= 1) {
        if (tid < w) {
            float m2 = sm[tid + w], s2 = ss[tid + w];
            float nm = fmaxf(sm[tid], m2);
            ss[tid] = ss[tid] * expf(sm[tid] - nm) + s2 * expf(m2 - nm);
            sm[tid] = nm;
        }
        __syncthreads();
    }
    float Rvv = sm[0] + logf(ss[0]);

    // phase 2: argmax(la+gumbel), entropy from LDS
    float bestg = -INFINITY;
    int bestj = 1 << 30;
    float ent = 0.f;
    #pragma unroll
    for (int k = 0; k < 4; ++k) {
        int j = tid + k * 256;
        float la = xs[j] - Rvv;
        ent += la * expf(la);
        float g = la + gr[j];
        if (g > bestg || (g == bestg && j < bestj)) { bestg = g; bestj = j; }
    }
    __shared__ float sg[256]; __shared__ int sj[256]; __shared__ float se[256];
    sg[tid] = bestg; sj[tid] = bestj; se[tid] = ent;
    __syncthreads();
    for (int w = 128; w > 0; w >>= 1) {
        if (tid < w) {
            se[tid] += se[tid + w];
            float g2 = sg[tid + w]; int j2 = sj[tid + w];
            if (g2 > sg[tid] || (g2 == sg[tid] && j2 < sj[tid])) {
                sg[tid] = g2; sj[tid] = j2;
            }
        }
        __syncthreads();
    }
    if (tid == 0) {
        int j = sj[0];
        out[r] = (float)j;
        out[16384 + r] = xs[j] - Rvv;
        out[32768 + r] = -se[0];
    }
}

// ---------------------------------------------------------------------------
extern "C" void kernel_launch(void* const* d_in, const int* in_sizes, int n_in,
                              void* d_out, int out_size, void* d_ws, size_t ws_size,
                              hipStream_t stream)
{
    const float* graph_emb = (const float*)d_in[0];
    const float* node_emb  = (const float*)d_in[1];
    const float* W_key     = (const float*)d_in[2];
    const float* rms_w     = (const float*)d_in[3];
    const float* W_in      = (const float*)d_in[4];
    const float* conv_w    = (const float*)d_in[5];
    const float* conv_b    = (const float*)d_in[6];
    const float* W_x       = (const float*)d_in[7];
    const float* W_dt      = (const float*)d_in[8];
    const float* b_dt      = (const float*)d_in[9];
    const float* A_log     = (const float*)d_in[10];
    const float* Dp        = (const float*)d_in[11];
    const float* W_out     = (const float*)d_in[12];
    const float* g_sink    = (const float*)d_in[13];
    const float* g_samp    = (const float*)d_in[14];
    float* out = (float*)d_out;

    // Workspace (floats). Total = 45,293,568 fl = 181.2 MB
    // (<= 45,531,136 fl proven in rounds 0-1).
    float* ws = (float*)d_ws;
    size_t o = 0;
    auto alloc = [&](size_t nf) { float* p = ws + o; o += nf; return p; };
    float* rs     = alloc(ROWS);                 // t0; Rv aliases later
    float* dbcBuf = alloc((size_t)ROWS * 56);    // dbc; Cvec/cpart alias later
    float* SCR    = alloc(3145728);              // W_inP (884736 fl) -> hin
    float* WPS    = alloc(516096);               // W_keyP (73728) + W_outP (442368)
    float* R1     = alloc((size_t)ROWS * 768);   // uB -> deltaB -> keysP
    float* R2     = alloc((size_t)ROWS * 768);   // ctxP -> uC/y -> la0 head
    float* R3     = alloc((size_t)ROWS * 768);   // zB -> la0 tail + queries
    float* Pbuf   = alloc(2949120);              // scan chunk products (15 slots)

    ushort* W_inP  = (ushort*)SCR;
    float*  hin    = SCR;
    ushort* W_keyP = (ushort*)WPS;
    ushort* W_outP = (ushort*)(WPS + 73728);
    ushort* ctxP   = (ushort*)R2;
    float*  uB     = R1;
    float*  deltaB = R1;
    ushort* keysP  = (ushort*)R1;
    float*  uC     = R2;
    float*  zB     = R3;
    float*  la0    = R2;                 // spans R2 + first 4,194,304 of R3
    float*  queries = R3 + 4194304;      // 6,291,456 fl, beyond la0 tail
    float*  Rv     = rs;
    float*  Cvec   = dbcBuf;
    float*  cpart  = dbcBuf + 16384;

    // 0. presplit weights + rms + ctx planes
    presplit_w_k<<<dim3(24, 3), 256, 0, stream>>>(W_in, 1536, W_inP, 1152);
    presplit_w_k<<<dim3(6, 1), 256, 0, stream>>>(W_key, 384, W_keyP, 384);
    presplit_w_k<<<dim3(6, 6), 256, 0, stream>>>(W_out, 384, W_outP, 2304);
    rms_k<<<dim3(ROWS), 128, 0, stream>>>(graph_emb, node_emb, rs);
    presplit_ctx_k<<<dim3(768), 256, 0, stream>>>(graph_emb, node_emb, rs, rms_w, ctxP);

    // 2a. uB = rmsnorm(ctx) @ W_in[:, :768]
    mgemm_p_k<0, 0, 0><<<dim3(6, 128), 256, 0, stream>>>(
        ctxP, nullptr, 0, 1152, 0, W_inP, nullptr, 0, 1152, 0,
        uB, nullptr, 768, 0, 0, 384, nullptr, nullptr, nullptr);

    // 2b. zB = rmsnorm(ctx) @ W_in[:, 768:]
    mgemm_p_k<0, 0, 0><<<dim3(6, 128), 256, 0, stream>>>(
        ctxP, nullptr, 0, 1152, 0, W_inP + (long long)768 * 1152, nullptr, 0, 1152, 0,
        zB, nullptr, 768, 0, 0, 384, nullptr, nullptr, nullptr);

    // 3. conv + silu -> uC (row-major)
    conv_r_k<<<dim3(16, 24, 16), 256, 0, stream>>>(uB, conv_w, conv_b, uC);

    // 4. dbc = u @ W_x  (dedicated skinny-N fp32 kernel, 256 blocks)
    dbc_k<<<dim3(256), 256, 0, stream>>>(uC, W_x, dbcBuf);

    // 5. deltaB = softplus(dbc_dt @ W_dt + b_dt[col])  (fp32, K=24)
    gemm_s_k<6><<<dim3(6, 128), 256, 0, stream>>>(
        dbcBuf, 56, W_dt, 768, deltaB, 768, ROWS, 768, 24, b_dt);

    // 6a. scan p0: per-chunk (P, Q) transfer functions (over W_inP, dead)
    scan_p0_k<<<dim3(3, 15, 16), 256, 0, stream>>>(
        deltaB, uC, dbcBuf, A_log, hin, Pbuf);

    // 6b. scan combine: checkpoints in place over hin
    scan_comb_k<<<dim3(3, 16, 16), 256, 0, stream>>>(hin, Pbuf);

    // 7. scan pass 2: gated y in-place over uC
    scan_p2_k<<<dim3(3, 16, 16), 256, 0, stream>>>(
        deltaB, uC, zB, dbcBuf, hin, A_log, Dp);

    // 8. keysP = planes(node_emb @ W_key)  (over deltaB, dead)
    mgemm_p_k<1, 0, 1><<<dim3(3, 128), 256, 0, stream>>>(
        nullptr, node_emb, 128, 0, 0, W_keyP, nullptr, 0, 384, 0,
        nullptr, keysP, 0, 1152, 0, 128, nullptr, nullptr, nullptr);

    // 9. queries = ctx + y @ W_out  (fp32, in R3 tail)
    mgemm_p_k<1, 0, 2><<<dim3(3, 128), 256, 0, stream>>>(
        nullptr, uC, 768, 0, 0, W_outP, nullptr, 0, 2304, 0,
        queries, nullptr, 384, 0, 0, 768, graph_emb, node_emb, nullptr);

    // 10. la0 = keys @ queries^T + gumbel_sink
    mgemm_p_k<0, 1, 3><<<dim3(8, 8, 16), 256, 0, stream>>>(
        keysP, nullptr, 0, 1152, (long long)1024 * 1152,
        nullptr, queries, 384, 0, (long long)1024 * 384,
        la0, nullptr, 1024, 0, (long long)1024 * 1024,
        384, nullptr, nullptr, g_sink);

    // 11. Sinkhorn: C1 = colLSE(la0); then 4x fused {R_i, colpart->C_{i+1}};
    //     R5 computed inside final2_k. 6 la0 sweeps total (was 11).
    zero_k<<<dim3(64), 256, 0, stream>>>(Rv, ROWS);
    col_lse_part<<<dim3(4, 16, 16), 256, 0, stream>>>(la0, Rv, (float2*)cpart);
    col_comb_k<<<dim3(64), 256, 0, stream>>>((const float2*)cpart, Cvec);
    for (int it = 0; it < 4; ++it) {
        sink_rowcol_k<<<dim3(16, 16), 512, 0, stream>>>(la0, Cvec, (float2*)cpart);
        col_comb_k<<<dim3(64), 256, 0, stream>>>((const float2*)cpart, Cvec);
    }

    // 12. outputs (R5 fused in)
    final2_k<<<dim3(ROWS), 256, 0, stream>>>(la0, Cvec, g_samp, out);
}

// Round 9
// 905.321 us; speedup vs baseline: 1.2318x; 1.2318x over previous
//
#include <hip/hip_runtime.h>
#include <math.h>

// Problem constants
#define Bsz 16
#define Nn  1024
#define Ee  128
#define CTX 384
#define DIN 768
#define DST 16
#define DTR 24
#define ROWS (Bsz*Nn)   // 16384

typedef __attribute__((ext_vector_type(8))) short short8;
typedef __attribute__((ext_vector_type(4))) float f32x4;

__device__ inline float fexp2(float x)
{
#if __has_builtin(__builtin_amdgcn_exp2f)
    return __builtin_amdgcn_exp2f(x);
#else
    return __expf(x * 0.6931471805599453f);
#endif
}

// ---------------------------------------------------------------------------
// split3: fp32 -> 3 bf16 planes (h trunc, m trunc, l rne). Product terms
// hh+hm+mh+hl+mm+lh give ~2^-23 rel error.
// ---------------------------------------------------------------------------
__device__ inline void split3(float v, ushort& h, ushort& m, ushort& l)
{
    unsigned u = __float_as_uint(v);
    h = (ushort)(u >> 16);
    float vh = __uint_as_float((unsigned)h << 16);
    float r = v - vh;
    unsigned ur = __float_as_uint(r);
    m = (ushort)(ur >> 16);
    float vm = __uint_as_float((unsigned)m << 16);
    float r2 = r - vm;
    unsigned u2 = __float_as_uint(r2);
    u2 += 0x7fffu + ((u2 >> 16) & 1u);
    l = (ushort)(u2 >> 16);
}

// ---------------------------------------------------------------------------
// RMS row scales over the virtual ctx = [graph_emb(256) | node_emb(128)]
// ---------------------------------------------------------------------------
__global__ __launch_bounds__(128) void rms_k(
    const float* __restrict__ ge, const float* __restrict__ ne,
    float* __restrict__ rs)
{
    int row = blockIdx.x;            // b*1024 + n
    int b = row >> 10;
    int tid = threadIdx.x;
    float ssq = 0.f;
    #pragma unroll
    for (int k = 0; k < 3; ++k) {
        int idx = tid + k * 128;
        float v = (idx < 256) ? ge[b * 256 + idx]
                              : ne[(long long)row * 128 + (idx - 256)];
        ssq += v * v;
    }
    __shared__ float sh[128];
    sh[tid] = ssq;
    __syncthreads();
    for (int w = 64; w > 0; w >>= 1) {
        if (tid < w) sh[tid] += sh[tid + w];
        __syncthreads();
    }
    if (tid == 0) rs[row] = rsqrtf(sh[0] * (1.f / 384.f) + 1e-6f);
}

__global__ __launch_bounds__(256) void zero_k(float* __restrict__ p, int n)
{
    int i = blockIdx.x * 256 + threadIdx.x;
    if (i < n) p[i] = 0.f;
}

// ---------------------------------------------------------------------------
// presplit_ctx_k: ctxP[row][kb][3][32] = split3(rmsnorm(ctx)).
// ---------------------------------------------------------------------------
__global__ __launch_bounds__(256) void presplit_ctx_k(
    const float* __restrict__ ge, const float* __restrict__ ne,
    const float* __restrict__ rs, const float* __restrict__ cw,
    ushort* __restrict__ ctxP)
{
    int idx = blockIdx.x * 256 + threadIdx.x;   // 0 .. 196607
    int row = idx / 12;
    int kb = idx - row * 12;
    float rsv = rs[row];
    int b = row >> 10;
    int c0 = kb * 32;
    ushort hb[32], mb[32], lb[32];
    #pragma unroll
    for (int e = 0; e < 32; ++e) {
        int col = c0 + e;
        float v = (col < 256) ? ge[b * 256 + col]
                              : ne[(long long)row * 128 + (col - 256)];
        v *= rsv * cw[col];
        split3(v, hb[e], mb[e], lb[e]);
    }
    ushort* dst = ctxP + (long long)row * 1152 + kb * 96;
    #pragma unroll
    for (int w8 = 0; w8 < 4; ++w8) {
        short8 v;
        #pragma unroll
        for (int e = 0; e < 8; ++e) v[e] = (short)hb[w8 * 8 + e];
        *(short8*)(dst + w8 * 8) = v;
    }
    #pragma unroll
    for (int w8 = 0; w8 < 4; ++w8) {
        short8 v;
        #pragma unroll
        for (int e = 0; e < 8; ++e) v[e] = (short)mb[w8 * 8 + e];
        *(short8*)(dst + 32 + w8 * 8) = v;
    }
    #pragma unroll
    for (int w8 = 0; w8 < 4; ++w8) {
        short8 v;
        #pragma unroll
        for (int e = 0; e < 8; ++e) v[e] = (short)lb[w8 * 8 + e];
        *(short8*)(dst + 64 + w8 * 8) = v;
    }
}

// ---------------------------------------------------------------------------
// presplit_w_k: W[K][N] fp32 -> WP[n][kb][3][32] (transposed plane format).
// ---------------------------------------------------------------------------
__global__ __launch_bounds__(256) void presplit_w_k(
    const float* __restrict__ W, int N, ushort* __restrict__ WP, int K3)
{
    int l = threadIdx.x & 63;
    int kq = threadIdx.x >> 6;
    int n = blockIdx.x * 64 + l;
    int kb = blockIdx.y * 4 + kq;
    ushort hb[32], mb[32], lb[32];
    #pragma unroll
    for (int i = 0; i < 32; ++i) {
        float v = W[(long long)(kb * 32 + i) * N + n];
        split3(v, hb[i], mb[i], lb[i]);
    }
    ushort* dst = WP + (long long)n * K3 + kb * 96;
    #pragma unroll
    for (int w8 = 0; w8 < 4; ++w8) {
        short8 v;
        #pragma unroll
        for (int e = 0; e < 8; ++e) v[e] = (short)hb[w8 * 8 + e];
        *(short8*)(dst + w8 * 8) = v;
    }
    #pragma unroll
    for (int w8 = 0; w8 < 4; ++w8) {
        short8 v;
        #pragma unroll
        for (int e = 0; e < 8; ++e) v[e] = (short)mb[w8 * 8 + e];
        *(short8*)(dst + 32 + w8 * 8) = v;
    }
    #pragma unroll
    for (int w8 = 0; w8 < 4; ++w8) {
        short8 v;
        #pragma unroll
        for (int e = 0; e < 8; ++e) v[e] = (short)lb[w8 * 8 + e];
        *(short8*)(dst + 64 + w8 * 8) = v;
    }
}

// ---------------------------------------------------------------------------
// mgemm_p_k: C = A @ B^T-planes, 128x128 tile, 4 waves, bf16x6 via 3 planes.
// ---------------------------------------------------------------------------
template<int ASRC, int BSRC, int EPI>
__global__ __launch_bounds__(256, 2) void mgemm_p_k(
    const ushort* __restrict__ PA, const float* __restrict__ Af,
    int ldaF, int sAp, long long aB,
    const ushort* __restrict__ PB, const float* __restrict__ Bf,
    int ldbF, int sBp, long long bB,
    float* __restrict__ Cf, ushort* __restrict__ CP,
    int ldc, int sCp, long long cB,
    int K,
    const float* __restrict__ ge, const float* __restrict__ ne,
    const float* __restrict__ gsink)
{
    __shared__ __align__(16) ushort As[128][128];
    __shared__ __align__(16) ushort Bs[128][128];
    int t = threadIdx.x;
    int n0 = blockIdx.x * 128, m0 = blockIdx.y * 128, bz = blockIdx.z;
    const ushort* pa = PA + (long long)bz * aB + (long long)m0 * sAp;
    const float*  fa = Af + (long long)bz * aB + (long long)m0 * ldaF;
    const ushort* pb = PB + (long long)bz * bB + (long long)n0 * sBp;
    const float*  fb = Bf + (long long)bz * bB + (long long)n0 * ldbF;

    int wave = t >> 6, lane = t & 63;
    int wm = (wave & 1) * 64, wn = (wave >> 1) * 64;
    int lm = lane & 15, lq = lane >> 4;
    f32x4 acc[4][4] = {};

    int nkb = K >> 5;
    for (int kb = 0; kb < nkb; ++kb) {
        int r = t >> 1;
        int sw = r & 15;
        // ---- stage A ----
        if (ASRC == 0) {
            int g0 = (t & 1) * 6;
            const ushort* src = pa + (long long)r * sAp + kb * 96 + g0 * 8;
            #pragma unroll
            for (int jj = 0; jj < 6; ++jj) {
                short8 v = *(const short8*)(src + jj * 8);
                *(short8*)&As[r][((g0 + jj) ^ sw) * 8] = v;
            }
        } else {
            int c0 = (t & 1) * 16;
            const float* src = fa + (long long)r * ldaF + kb * 32 + c0;
            ushort hb[16], mb[16], lb[16];
            #pragma unroll
            for (int e = 0; e < 16; ++e) split3(src[e], hb[e], mb[e], lb[e]);
            int gq = (t & 1) * 2;
            #pragma unroll
            for (int half = 0; half < 2; ++half) {
                short8 vh, vm, vl;
                #pragma unroll
                for (int e = 0; e < 8; ++e) {
                    vh[e] = (short)hb[half * 8 + e];
                    vm[e] = (short)mb[half * 8 + e];
                    vl[e] = (short)lb[half * 8 + e];
                }
                *(short8*)&As[r][((0 + gq + half) ^ sw) * 8] = vh;
                *(short8*)&As[r][((4 + gq + half) ^ sw) * 8] = vm;
                *(short8*)&As[r][((8 + gq + half) ^ sw) * 8] = vl;
            }
        }
        // ---- stage B ----
        if (BSRC == 0) {
            int g0 = (t & 1) * 6;
            const ushort* src = pb + (long long)r * sBp + kb * 96 + g0 * 8;
            #pragma unroll
            for (int jj = 0; jj < 6; ++jj) {
                short8 v = *(const short8*)(src + jj * 8);
                *(short8*)&Bs[r][((g0 + jj) ^ sw) * 8] = v;
            }
        } else {
            int c0 = (t & 1) * 16;
            const float* src = fb + (long long)r * ldbF + kb * 32 + c0;
            ushort hb[16], mb[16], lb[16];
            #pragma unroll
            for (int e = 0; e < 16; ++e) split3(src[e], hb[e], mb[e], lb[e]);
            int gq = (t & 1) * 2;
            #pragma unroll
            for (int half = 0; half < 2; ++half) {
                short8 vh, vm, vl;
                #pragma unroll
                for (int e = 0; e < 8; ++e) {
                    vh[e] = (short)hb[half * 8 + e];
                    vm[e] = (short)mb[half * 8 + e];
                    vl[e] = (short)lb[half * 8 + e];
                }
                *(short8*)&Bs[r][((0 + gq + half) ^ sw) * 8] = vh;
                *(short8*)&Bs[r][((4 + gq + half) ^ sw) * 8] = vm;
                *(short8*)&Bs[r][((8 + gq + half) ^ sw) * 8] = vl;
            }
        }
        __syncthreads();
        // ---- fragments + 6-term MFMA ----
        short8 ah[4], am[4], al[4];
        #pragma unroll
        for (int i = 0; i < 4; ++i) {
            int R = wm + i * 16 + lm;
            int rw = R & 15;
            ah[i] = *(const short8*)&As[R][((0 + lq) ^ rw) * 8];
            am[i] = *(const short8*)&As[R][((4 + lq) ^ rw) * 8];
            al[i] = *(const short8*)&As[R][((8 + lq) ^ rw) * 8];
        }
        #pragma unroll
        for (int j = 0; j < 4; ++j) {
            int Rn = wn + j * 16 + lm;
            int rw = Rn & 15;
            short8 bh = *(const short8*)&Bs[Rn][((0 + lq) ^ rw) * 8];
            short8 bm = *(const short8*)&Bs[Rn][((4 + lq) ^ rw) * 8];
            short8 bl = *(const short8*)&Bs[Rn][((8 + lq) ^ rw) * 8];
            #pragma unroll
            for (int i = 0; i < 4; ++i)
                acc[i][j] = __builtin_amdgcn_mfma_f32_16x16x32_bf16(ah[i], bh, acc[i][j], 0, 0, 0);
            #pragma unroll
            for (int i = 0; i < 4; ++i)
                acc[i][j] = __builtin_amdgcn_mfma_f32_16x16x32_bf16(ah[i], bm, acc[i][j], 0, 0, 0);
            #pragma unroll
            for (int i = 0; i < 4; ++i)
                acc[i][j] = __builtin_amdgcn_mfma_f32_16x16x32_bf16(am[i], bh, acc[i][j], 0, 0, 0);
            #pragma unroll
            for (int i = 0; i < 4; ++i)
                acc[i][j] = __builtin_amdgcn_mfma_f32_16x16x32_bf16(ah[i], bl, acc[i][j], 0, 0, 0);
            #pragma unroll
            for (int i = 0; i < 4; ++i)
                acc[i][j] = __builtin_amdgcn_mfma_f32_16x16x32_bf16(am[i], bm, acc[i][j], 0, 0, 0);
            #pragma unroll
            for (int i = 0; i < 4; ++i)
                acc[i][j] = __builtin_amdgcn_mfma_f32_16x16x32_bf16(al[i], bh, acc[i][j], 0, 0, 0);
        }
        __syncthreads();
    }

    // ---- epilogue: D col=lane&15, row=lq*4+reg ----
    #pragma unroll
    for (int i = 0; i < 4; ++i) {
        #pragma unroll
        for (int rg = 0; rg < 4; ++rg) {
            int m = m0 + wm + i * 16 + lq * 4 + rg;
            #pragma unroll
            for (int j = 0; j < 4; ++j) {
                int n = n0 + wn + j * 16 + lm;
                float x = acc[i][j][rg];
                if (EPI == 0) {
                    Cf[(long long)m * ldc + n] = x;
                } else if (EPI == 1) {
                    ushort h, mm_, l;
                    split3(x, h, mm_, l);
                    ushort* dst = CP + (long long)m * sCp + (n >> 5) * 96 + (n & 31);
                    dst[0] = h; dst[32] = mm_; dst[64] = l;
                } else if (EPI == 2) {
                    x += (n < 256) ? ge[(m >> 10) * 256 + n]
                                   : ne[(long long)m * 128 + (n - 256)];
                    Cf[(long long)m * ldc + n] = x;
                } else {
                    long long off = (long long)bz * cB + (long long)m * ldc + n;
                    Cf[off] = x + gsink[off];
                }
            }
        }
    }
}

// ---------------------------------------------------------------------------
// dbc_k: dbc[16384][56] = uC[16384][768] @ W_x[768][56]. Skinny-N fp32 GEMM.
// ---------------------------------------------------------------------------
__global__ __launch_bounds__(256) void dbc_k(
    const float* __restrict__ uC, const float* __restrict__ Wx,
    float* __restrict__ dbc)
{
    __shared__ float As[32][68];   // [k][row], 64 rows padded to 68
    __shared__ float Bs[32][64];   // [k][col], 56 cols padded to 64
    int t = threadIdx.x;
    int r0 = blockIdx.x * 64;
    int tr = t >> 4, tc = t & 15;
    float acc[4][4] = {};

    for (int k0 = 0; k0 < 768; k0 += 32) {
        #pragma unroll
        for (int i = 0; i < 2; ++i) {
            int idx = t + i * 256;           // 0..511
            int r = idx >> 3;                // 0..63
            int kq = (idx & 7) * 4;          // 0..28
            float4 v = *(const float4*)(uC + (long long)(r0 + r) * 768 + k0 + kq);
            As[kq + 0][r] = v.x;
            As[kq + 1][r] = v.y;
            As[kq + 2][r] = v.z;
            As[kq + 3][r] = v.w;
        }
        #pragma unroll
        for (int i = 0; i < 2; ++i) {
            int idx = t + i * 256;           // need 32*14 = 448
            if (idx < 448) {
                int kk = idx / 14;
                int c4 = (idx - kk * 14) * 4;
                float4 v = *(const float4*)(Wx + (long long)(k0 + kk) * 56 + c4);
                *(float4*)&Bs[kk][c4] = v;
            }
        }
        __syncthreads();
        #pragma unroll
        for (int kk = 0; kk < 32; ++kk) {
            float4 a = *(const float4*)&As[kk][tr * 4];
            float4 b = *(const float4*)&Bs[kk][tc * 4];
            float av[4] = {a.x, a.y, a.z, a.w};
            float bv[4] = {b.x, b.y, b.z, b.w};
            #pragma unroll
            for (int i = 0; i < 4; ++i)
                #pragma unroll
                for (int j = 0; j < 4; ++j)
                    acc[i][j] = fmaf(av[i], bv[j], acc[i][j]);
        }
        __syncthreads();
    }

    if (tc < 14) {                           // cols tc*4..tc*4+3 < 56
        #pragma unroll
        for (int i = 0; i < 4; ++i) {
            int row = r0 + tr * 4 + i;
            *(float4*)&dbc[(long long)row * 56 + tc * 4] =
                make_float4(acc[i][0], acc[i][1], acc[i][2], acc[i][3]);
        }
    }
}

// ---------------------------------------------------------------------------
// delta_k: deltaB[16384][768] = softplus(dbc[:, :24] @ W_dt + b_dt).
// K=24 is tiny: weights live in registers (thread owns cols d, d+256, d+512;
// 72 w + 3 bias VGPRs, reused over rows). Per row: one wave-uniform 24-float
// dbc read, 3 sequential 24-fma chains (same k order as the old GEMM ->
// bit-identical dot), same softplus formula -> bit-identical delta.
// Grid 1024 blocks x 16 rows. No LDS, no barriers.
// ---------------------------------------------------------------------------
__global__ __launch_bounds__(256) void delta_k(
    const float* __restrict__ dbc, const float* __restrict__ Wdt,
    const float* __restrict__ bdt, float* __restrict__ deltaB)
{
    int t = threadIdx.x;
    int r0 = blockIdx.x * 16;
    float w[3][24], bb[3];
    #pragma unroll
    for (int q = 0; q < 3; ++q) {
        int d = t + q * 256;
        bb[q] = bdt[d];
        #pragma unroll
        for (int k = 0; k < 24; ++k)
            w[q][k] = Wdt[k * 768 + d];       // coalesced across threads
    }
    for (int rr = 0; rr < 16; ++rr) {
        int row = __builtin_amdgcn_readfirstlane(r0 + rr);
        const float* br = dbc + (long long)row * 56;
        float dt[24];
        #pragma unroll
        for (int k6 = 0; k6 < 6; ++k6) {
            float4 v = *(const float4*)(br + k6 * 4);
            dt[k6 * 4 + 0] = v.x; dt[k6 * 4 + 1] = v.y;
            dt[k6 * 4 + 2] = v.z; dt[k6 * 4 + 3] = v.w;
        }
        #pragma unroll
        for (int q = 0; q < 3; ++q) {
            float acc = 0.f;
            #pragma unroll
            for (int k = 0; k < 24; ++k)
                acc = fmaf(dt[k], w[q][k], acc);
            float s = acc + bb[q];
            float x = fmaxf(s, 0.f) + log1pf(expf(-fabsf(s)));
            deltaB[(long long)row * 768 + t + q * 256] = x;
        }
    }
}

// ---------------------------------------------------------------------------
// Depthwise causal conv (K=4) + bias + SiLU, ROW-MAJOR out: uC[b*1024+n][d]
// ---------------------------------------------------------------------------
__global__ __launch_bounds__(256) void conv_r_k(
    const float* __restrict__ uB, const float* __restrict__ cw,
    const float* __restrict__ cb, float* __restrict__ uC)
{
    __shared__ float tile[67][33];
    int b = blockIdx.z, d0 = blockIdx.y * 32, n0 = blockIdx.x * 64;
    int tid = threadIdx.x;
    for (int i = tid; i < 67 * 32; i += 256) {
        int r = i >> 5, c = i & 31;
        int n = n0 - 3 + r;
        tile[r][c] = (n >= 0) ? uB[((long long)(b * 1024 + n)) * 768 + d0 + c] : 0.f;
    }
    __syncthreads();
    int dc = tid & 31;
    int nr = tid >> 5;
    int d = d0 + dc;
    float w0 = cw[d * 4 + 0], w1 = cw[d * 4 + 1];
    float w2 = cw[d * 4 + 2], w3 = cw[d * 4 + 3];
    float bb = cb[d];
    #pragma unroll
    for (int it = 0; it < 8; ++it) {
        int nl = nr + it * 8;
        float acc = bb;
        acc = fmaf(tile[nl][dc],     w0, acc);
        acc = fmaf(tile[nl + 1][dc], w1, acc);
        acc = fmaf(tile[nl + 2][dc], w2, acc);
        acc = fmaf(tile[nl + 3][dc], w3, acc);
        float sv = acc / (1.f + __expf(-acc));
        uC[((long long)(b * 1024 + n0 + nl)) * 768 + d] = sv;
    }
}

// ---------------------------------------------------------------------------
// S6 scan, associative 3-phase, ROW-MAJOR delta/u/z/y.
// ---------------------------------------------------------------------------
#define HIN_CSTR (16LL * 16 * 768)   // floats per chunk slot

__global__ __launch_bounds__(256) void scan_p0_k(
    const float* __restrict__ dB, const float* __restrict__ uC,
    const float* __restrict__ dbc, const float* __restrict__ A_log,
    float* __restrict__ hin, float* __restrict__ Pbuf)
{
    int d = blockIdx.x * 256 + threadIdx.x;
    int c = blockIdx.y;              // 0..14
    int b = blockIdx.z;
    int n0 = c * 64;
    long long rowbase = (long long)b * 1024 + n0;
    const float* dR = dB + rowbase * 768 + d;
    const float* uR = uC + rowbase * 768 + d;

    float a2[16], P[16], Q[16];
    #pragma unroll
    for (int s = 0; s < 16; ++s) {
        a2[s] = -__expf(A_log[d * 16 + s]) * 1.44269504088896340736f;
        P[s] = 1.f;
        Q[s] = 0.f;
    }

    for (int i0 = 0; i0 < 64; i0 += 4) {
        float dv[4], uv[4];
        #pragma unroll
        for (int j = 0; j < 4; ++j) {
            long long i = i0 + j;
            dv[j] = dR[i * 768];
            uv[j] = uR[i * 768];
        }
        #pragma unroll
        for (int j = 0; j < 4; ++j) {
            int row = __builtin_amdgcn_readfirstlane((int)rowbase + i0 + j);
            const float* br = dbc + (long long)row * 56;
            float Bv[16];
            #pragma unroll
            for (int q = 0; q < 4; ++q) {
                float4 bq = *(const float4*)(br + 24 + q * 4);
                Bv[q * 4 + 0] = bq.x; Bv[q * 4 + 1] = bq.y;
                Bv[q * 4 + 2] = bq.z; Bv[q * 4 + 3] = bq.w;
            }
            float x = dv[j] * uv[j];
            #pragma unroll
            for (int s = 0; s < 16; ++s) {
                float dA = fexp2(dv[j] * a2[s]);
                Q[s] = fmaf(dA, Q[s], x * Bv[s]);
                P[s] *= dA;
            }
        }
    }

    float* qd = hin  + (long long)(c + 1) * HIN_CSTR + ((long long)b * 16) * 768 + d;
    float* pd = Pbuf + (long long)c * HIN_CSTR + ((long long)b * 16) * 768 + d;
    #pragma unroll
    for (int s = 0; s < 16; ++s) {
        qd[(long long)s * 768] = Q[s];
        pd[(long long)s * 768] = P[s];
    }
}

__global__ __launch_bounds__(256) void scan_comb_k(
    float* __restrict__ hin, const float* __restrict__ Pbuf)
{
    int d = blockIdx.x * 256 + threadIdx.x;
    int s = blockIdx.y, b = blockIdx.z;
    long long off = ((long long)b * 16 + s) * 768 + d;
    float h = 0.f;
    hin[off] = 0.f;                          // chunk 0 checkpoint
    #pragma unroll
    for (int c = 1; c < 16; ++c) {
        float q = hin[(long long)c * HIN_CSTR + off];
        float p = Pbuf[(long long)(c - 1) * HIN_CSTR + off];
        h = fmaf(p, h, q);
        hin[(long long)c * HIN_CSTR + off] = h;
    }
}

__global__ __launch_bounds__(256) void scan_p2_k(
    const float* __restrict__ dB, float* uyC, const float* __restrict__ zB,
    const float* __restrict__ dbc, const float* __restrict__ hin,
    const float* __restrict__ A_log, const float* __restrict__ Dp)
{
    int d = blockIdx.x * 256 + threadIdx.x;
    int c = blockIdx.y;
    int b = blockIdx.z;
    int n0 = c * 64;
    long long rowbase = (long long)b * 1024 + n0;
    const float* dR = dB  + rowbase * 768 + d;
    const float* uR = uyC + rowbase * 768 + d;
    const float* zR = zB  + rowbase * 768 + d;
    float*       yR = uyC + rowbase * 768 + d;

    float a2[16], h[16];
    #pragma unroll
    for (int s = 0; s < 16; ++s)
        a2[s] = -__expf(A_log[d * 16 + s]) * 1.44269504088896340736f;
    const float* hp = hin + (long long)c * HIN_CSTR + ((long long)b * 16) * 768 + d;
    #pragma unroll
    for (int s = 0; s < 16; ++s)
        h[s] = hp[(long long)s * 768];
    float dp = Dp[d];

    for (int i0 = 0; i0 < 64; i0 += 4) {
        float dv[4], uv[4], zv[4];
        #pragma unroll
        for (int j = 0; j < 4; ++j) {
            long long i = i0 + j;
            dv[j] = dR[i * 768];
            uv[j] = uR[i * 768];
            zv[j] = zR[i * 768];
        }
        float ya[4];
        #pragma unroll
        for (int j = 0; j < 4; ++j) {
            int row = __builtin_amdgcn_readfirstlane((int)rowbase + i0 + j);
            const float* br = dbc + (long long)row * 56;
            float Bv[16], Cv[16];
            #pragma unroll
            for (int q = 0; q < 4; ++q) {
                float4 bq = *(const float4*)(br + 24 + q * 4);
                float4 cq = *(const float4*)(br + 40 + q * 4);
                Bv[q * 4 + 0] = bq.x; Bv[q * 4 + 1] = bq.y;
                Bv[q * 4 + 2] = bq.z; Bv[q * 4 + 3] = bq.w;
                Cv[q * 4 + 0] = cq.x; Cv[q * 4 + 1] = cq.y;
                Cv[q * 4 + 2] = cq.z; Cv[q * 4 + 3] = cq.w;
            }
            float x = dv[j] * uv[j];
            float y = 0.f;
            #pragma unroll
            for (int s = 0; s < 16; ++s) {
                float dA = fexp2(dv[j] * a2[s]);
                h[s] = fmaf(dA, h[s], x * Bv[s]);
                y = fmaf(h[s], Cv[s], y);
            }
            float z = zv[j];
            ya[j] = (y + dp * uv[j]) * (z / (1.f + __expf(-z)));
        }
        #pragma unroll
        for (int j = 0; j < 4; ++j)
            yR[(long long)(i0 + j) * 768] = ya[j];
    }
}

// ---------------------------------------------------------------------------
// Sinkhorn on la = la0 - R_i - C_j (never materialized).
// col_lse_part: initial col pass (R = 0 vector). col_comb_k: chunk combine.
// sink_rowcol_k: FUSED row pass + next col partials, one la0 read.
// final2_k: computes R5 in-kernel, then argmax/log_prob/entropy.
// ---------------------------------------------------------------------------
__global__ __launch_bounds__(256) void col_lse_part(
    const float* __restrict__ la0, const float* __restrict__ R,
    float2* __restrict__ cpart)
{
    int j = blockIdx.x * 256 + threadIdx.x;
    int ch = blockIdx.y;
    int b = blockIdx.z;
    const float* base = la0 + (long long)b * 1024 * 1024 + (long long)ch * 64 * 1024 + j;
    const float* Rb = R + b * 1024 + ch * 64;
    float m = -INFINITY, sum = 0.f;
    for (int i = 0; i < 64; ++i) {
        float x = base[(long long)i * 1024] - Rb[i];
        float nm = fmaxf(m, x);
        sum = sum * expf(m - nm) + expf(x - nm);
        m = nm;
    }
    cpart[(long long)(b * 16 + ch) * 1024 + j] = make_float2(m, sum);
}

__global__ __launch_bounds__(256) void col_comb_k(
    const float2* __restrict__ cpart, float* __restrict__ Cv)
{
    int idx = blockIdx.x * 256 + threadIdx.x;
    int b = idx >> 10, j = idx & 1023;
    float m = -INFINITY, sum = 0.f;
    #pragma unroll
    for (int ch = 0; ch < 16; ++ch) {
        float2 p = cpart[(long long)(b * 16 + ch) * 1024 + j];
        float nm = fmaxf(m, p.x);
        sum = sum * expf(m - nm) + p.y * expf(p.x - nm);
        m = nm;
    }
    Cv[idx] = m + logf(sum);
}

__global__ __launch_bounds__(512) void sink_rowcol_k(
    const float* __restrict__ la0, const float* __restrict__ Cv,
    float2* __restrict__ cpart)
{
    __shared__ float cmS[8][1024];
    __shared__ float csS[8][1024];
    int t = threadIdx.x;
    int wave = t >> 6, lane = t & 63;
    int ch = blockIdx.x, b = blockIdx.y;
    const float* base = la0 + (long long)b * (1024 * 1024)
                      + (long long)(ch * 64 + wave * 8) * 1024;
    const float* Cb = Cv + b * 1024;

    float cv[16];
    #pragma unroll
    for (int q = 0; q < 4; ++q) {
        float4 c4 = *(const float4*)(Cb + q * 256 + lane * 4);
        cv[q * 4 + 0] = c4.x; cv[q * 4 + 1] = c4.y;
        cv[q * 4 + 2] = c4.z; cv[q * 4 + 3] = c4.w;
    }
    float cm[16], cs[16];
    #pragma unroll
    for (int k = 0; k < 16; ++k) { cm[k] = -INFINITY; cs[k] = 0.f; }

    for (int rr = 0; rr < 8; ++rr) {
        const float* row = base + (long long)rr * 1024;
        float v[16];
        #pragma unroll
        for (int q = 0; q < 4; ++q) {
            float4 r4 = *(const float4*)(row + q * 256 + lane * 4);
            v[q * 4 + 0] = r4.x; v[q * 4 + 1] = r4.y;
            v[q * 4 + 2] = r4.z; v[q * 4 + 3] = r4.w;
        }
        // row LSE over (v - cv), wave-wide
        float m = -INFINITY;
        #pragma unroll
        for (int k = 0; k < 16; ++k) m = fmaxf(m, v[k] - cv[k]);
        float s = 0.f;
        #pragma unroll
        for (int k = 0; k < 16; ++k) s += expf(v[k] - cv[k] - m);
        #pragma unroll
        for (int off = 1; off < 64; off <<= 1) {
            float m2 = __shfl_xor(m, off);
            float s2 = __shfl_xor(s, off);
            float nm = fmaxf(m, m2);
            s = s * expf(m - nm) + s2 * expf(m2 - nm);
            m = nm;
        }
        float R = m + logf(s);
        // col partial update with val = v - R
        #pragma unroll
        for (int k = 0; k < 16; ++k) {
            float val = v[k] - R;
            float nm = fmaxf(cm[k], val);
            cs[k] = cs[k] * expf(cm[k] - nm) + expf(val - nm);
            cm[k] = nm;
        }
    }
    // stash wave-local col partials
    #pragma unroll
    for (int q = 0; q < 4; ++q) {
        *(float4*)&cmS[wave][q * 256 + lane * 4] =
            make_float4(cm[q * 4 + 0], cm[q * 4 + 1], cm[q * 4 + 2], cm[q * 4 + 3]);
        *(float4*)&csS[wave][q * 256 + lane * 4] =
            make_float4(cs[q * 4 + 0], cs[q * 4 + 1], cs[q * 4 + 2], cs[q * 4 + 3]);
    }
    __syncthreads();
    // combine 8 waves per column; 512 threads x 2 cols
    #pragma unroll
    for (int jj = 0; jj < 2; ++jj) {
        int j = t * 2 + jj;
        float m = -INFINITY, s = 0.f;
        #pragma unroll
        for (int w = 0; w < 8; ++w) {
            float m2 = cmS[w][j], s2 = csS[w][j];
            float nm = fmaxf(m, m2);
            s = s * expf(m - nm) + s2 * expf(m2 - nm);
            m = nm;
        }
        cpart[(long long)(b * 16 + ch) * 1024 + j] = make_float2(m, s);
    }
}

__global__ __launch_bounds__(256) void final2_k(
    const float* __restrict__ la0, const float* __restrict__ Cv,
    const float* __restrict__ gs, float* __restrict__ out)
{
    int r = blockIdx.x;
    int b = r >> 10;
    const float* row = la0 + (long long)r * 1024;
    const float* gr = gs + (long long)r * 1024;
    const float* Cb = Cv + b * 1024;
    int tid = threadIdx.x;
    __shared__ float xs[1024];
    __shared__ float sm[256], ss[256];

    // phase 1: x = row - C5, stash in LDS, row LSE -> R5
    float m = -INFINITY, s = 0.f;
    #pragma unroll
    for (int k = 0; k < 4; ++k) {
        int j = tid + k * 256;
        float x = row[j] - Cb[j];
        xs[j] = x;
        float nm = fmaxf(m, x);
        s = s * expf(m - nm) + expf(x - nm);
        m = nm;
    }
    sm[tid] = m; ss[tid] = s;
    __syncthreads();
    for (int w = 128; w > 0; w >>= 1) {
        if (tid < w) {
            float m2 = sm[tid + w], s2 = ss[tid + w];
            float nm = fmaxf(sm[tid], m2);
            ss[tid] = ss[tid] * expf(sm[tid] - nm) + s2 * expf(m2 - nm);
            sm[tid] = nm;
        }
        __syncthreads();
    }
    float Rvv = sm[0] + logf(ss[0]);

    // phase 2: argmax(la+gumbel), entropy from LDS
    float bestg = -INFINITY;
    int bestj = 1 << 30;
    float ent = 0.f;
    #pragma unroll
    for (int k = 0; k < 4; ++k) {
        int j = tid + k * 256;
        float la = xs[j] - Rvv;
        ent += la * expf(la);
        float g = la + gr[j];
        if (g > bestg || (g == bestg && j < bestj)) { bestg = g; bestj = j; }
    }
    __shared__ float sg[256]; __shared__ int sj[256]; __shared__ float se[256];
    sg[tid] = bestg; sj[tid] = bestj; se[tid] = ent;
    __syncthreads();
    for (int w = 128; w > 0; w >>= 1) {
        if (tid < w) {
            se[tid] += se[tid + w];
            float g2 = sg[tid + w]; int j2 = sj[tid + w];
            if (g2 > sg[tid] || (g2 == sg[tid] && j2 < sj[tid])) {
                sg[tid] = g2; sj[tid] = j2;
            }
        }
        __syncthreads();
    }
    if (tid == 0) {
        int j = sj[0];
        out[r] = (float)j;
        out[16384 + r] = xs[j] - Rvv;
        out[32768 + r] = -se[0];
    }
}

// ---------------------------------------------------------------------------
extern "C" void kernel_launch(void* const* d_in, const int* in_sizes, int n_in,
                              void* d_out, int out_size, void* d_ws, size_t ws_size,
                              hipStream_t stream)
{
    const float* graph_emb = (const float*)d_in[0];
    const float* node_emb  = (const float*)d_in[1];
    const float* W_key     = (const float*)d_in[2];
    const float* rms_w     = (const float*)d_in[3];
    const float* W_in      = (const float*)d_in[4];
    const float* conv_w    = (const float*)d_in[5];
    const float* conv_b    = (const float*)d_in[6];
    const float* W_x       = (const float*)d_in[7];
    const float* W_dt      = (const float*)d_in[8];
    const float* b_dt      = (const float*)d_in[9];
    const float* A_log     = (const float*)d_in[10];
    const float* Dp        = (const float*)d_in[11];
    const float* W_out     = (const float*)d_in[12];
    const float* g_sink    = (const float*)d_in[13];
    const float* g_samp    = (const float*)d_in[14];
    float* out = (float*)d_out;

    // Workspace (floats). Total = 45,293,568 fl = 181.2 MB
    // (<= 45,531,136 fl proven in rounds 0-1).
    float* ws = (float*)d_ws;
    size_t o = 0;
    auto alloc = [&](size_t nf) { float* p = ws + o; o += nf; return p; };
    float* rs     = alloc(ROWS);                 // t0; Rv aliases later
    float* dbcBuf = alloc((size_t)ROWS * 56);    // dbc; Cvec/cpart alias later
    float* SCR    = alloc(3145728);              // W_inP (884736 fl) -> hin
    float* WPS    = alloc(516096);               // W_keyP (73728) + W_outP (442368)
    float* R1     = alloc((size_t)ROWS * 768);   // uB -> deltaB -> keysP
    float* R2     = alloc((size_t)ROWS * 768);   // ctxP -> uC/y -> la0 head
    float* R3     = alloc((size_t)ROWS * 768);   // zB -> la0 tail + queries
    float* Pbuf   = alloc(2949120);              // scan chunk products (15 slots)

    ushort* W_inP  = (ushort*)SCR;
    float*  hin    = SCR;
    ushort* W_keyP = (ushort*)WPS;
    ushort* W_outP = (ushort*)(WPS + 73728);
    ushort* ctxP   = (ushort*)R2;
    float*  uB     = R1;
    float*  deltaB = R1;
    ushort* keysP  = (ushort*)R1;
    float*  uC     = R2;
    float*  zB     = R3;
    float*  la0    = R2;                 // spans R2 + first 4,194,304 of R3
    float*  queries = R3 + 4194304;      // 6,291,456 fl, beyond la0 tail
    float*  Rv     = rs;
    float*  Cvec   = dbcBuf;
    float*  cpart  = dbcBuf + 16384;

    // 0. presplit weights + rms + ctx planes
    presplit_w_k<<<dim3(24, 3), 256, 0, stream>>>(W_in, 1536, W_inP, 1152);
    presplit_w_k<<<dim3(6, 1), 256, 0, stream>>>(W_key, 384, W_keyP, 384);
    presplit_w_k<<<dim3(6, 6), 256, 0, stream>>>(W_out, 384, W_outP, 2304);
    rms_k<<<dim3(ROWS), 128, 0, stream>>>(graph_emb, node_emb, rs);
    presplit_ctx_k<<<dim3(768), 256, 0, stream>>>(graph_emb, node_emb, rs, rms_w, ctxP);

    // 2a. uB = rmsnorm(ctx) @ W_in[:, :768]
    mgemm_p_k<0, 0, 0><<<dim3(6, 128), 256, 0, stream>>>(
        ctxP, nullptr, 0, 1152, 0, W_inP, nullptr, 0, 1152, 0,
        uB, nullptr, 768, 0, 0, 384, nullptr, nullptr, nullptr);

    // 2b. zB = rmsnorm(ctx) @ W_in[:, 768:]
    mgemm_p_k<0, 0, 0><<<dim3(6, 128), 256, 0, stream>>>(
        ctxP, nullptr, 0, 1152, 0, W_inP + (long long)768 * 1152, nullptr, 0, 1152, 0,
        zB, nullptr, 768, 0, 0, 384, nullptr, nullptr, nullptr);

    // 3. conv + silu -> uC (row-major)
    conv_r_k<<<dim3(16, 24, 16), 256, 0, stream>>>(uB, conv_w, conv_b, uC);

    // 4. dbc = u @ W_x  (dedicated skinny-N fp32 kernel, 256 blocks)
    dbc_k<<<dim3(256), 256, 0, stream>>>(uC, W_x, dbcBuf);

    // 5. deltaB = softplus(dbc_dt @ W_dt + b_dt)  (register-resident K=24)
    delta_k<<<dim3(1024), 256, 0, stream>>>(dbcBuf, W_dt, b_dt, deltaB);

    // 6a. scan p0: per-chunk (P, Q) transfer functions (over W_inP, dead)
    scan_p0_k<<<dim3(3, 15, 16), 256, 0, stream>>>(
        deltaB, uC, dbcBuf, A_log, hin, Pbuf);

    // 6b. scan combine: checkpoints in place over hin
    scan_comb_k<<<dim3(3, 16, 16), 256, 0, stream>>>(hin, Pbuf);

    // 7. scan pass 2: gated y in-place over uC
    scan_p2_k<<<dim3(3, 16, 16), 256, 0, stream>>>(
        deltaB, uC, zB, dbcBuf, hin, A_log, Dp);

    // 8. keysP = planes(node_emb @ W_key)  (over deltaB, dead)
    mgemm_p_k<1, 0, 1><<<dim3(3, 128), 256, 0, stream>>>(
        nullptr, node_emb, 128, 0, 0, W_keyP, nullptr, 0, 384, 0,
        nullptr, keysP, 0, 1152, 0, 128, nullptr, nullptr, nullptr);

    // 9. queries = ctx + y @ W_out  (fp32, in R3 tail)
    mgemm_p_k<1, 0, 2><<<dim3(3, 128), 256, 0, stream>>>(
        nullptr, uC, 768, 0, 0, W_outP, nullptr, 0, 2304, 0,
        queries, nullptr, 384, 0, 0, 768, graph_emb, node_emb, nullptr);

    // 10. la0 = keys @ queries^T + gumbel_sink
    mgemm_p_k<0, 1, 3><<<dim3(8, 8, 16), 256, 0, stream>>>(
        keysP, nullptr, 0, 1152, (long long)1024 * 1152,
        nullptr, queries, 384, 0, (long long)1024 * 384,
        la0, nullptr, 1024, 0, (long long)1024 * 1024,
        384, nullptr, nullptr, g_sink);

    // 11. Sinkhorn: C1 = colLSE(la0); then 4x fused {R_i, colpart->C_{i+1}};
    //     R5 computed inside final2_k. 6 la0 sweeps total (was 11).
    zero_k<<<dim3(64), 256, 0, stream>>>(Rv, ROWS);
    col_lse_part<<<dim3(4, 16, 16), 256, 0, stream>>>(la0, Rv, (float2*)cpart);
    col_comb_k<<<dim3(64), 256, 0, stream>>>((const float2*)cpart, Cvec);
    for (int it = 0; it < 4; ++it) {
        sink_rowcol_k<<<dim3(16, 16), 512, 0, stream>>>(la0, Cvec, (float2*)cpart);
        col_comb_k<<<dim3(64), 256, 0, stream>>>((const float2*)cpart, Cvec);
    }

    // 12. outputs (R5 fused in)
    final2_k<<<dim3(ROWS), 256, 0, stream>>>(la0, Cvec, g_samp, out);
}